// Round 1
// baseline (290.134 us; speedup 1.0000x reference)
//
#include <hip/hip_runtime.h>
#include <hip/hip_bf16.h>
#include <math.h>

#define EN 8192
#define EL 8192
#define D  256
#define NG 64
#define INF_BITS 0x7f800000u

typedef __attribute__((ext_vector_type(8))) short  bf16x8;
typedef __attribute__((ext_vector_type(4))) float  f32x4;

__device__ __forceinline__ unsigned short f2bf(float f) {
    unsigned u = __float_as_uint(f);
    unsigned r = (u + 0x7fffu + ((u >> 16) & 1u)) >> 16;   // RNE
    return (unsigned short)r;
}

// ---------------- kernel 0: init min-buffers to +inf ----------------
__global__ void init_inf(unsigned* __restrict__ p, int n) {
    int i = blockIdx.x * blockDim.x + threadIdx.x;
    if (i < n) p[i] = INF_BITS;
}

// ---------------- kernel 1: edge features + norms ----------------
// One wave per edge: ef = 0.5*(h[a]+h[b]); store bf16; norm = sum(ef^2) fp32.
__global__ void edge_feat(const float* __restrict__ h,
                          const int* __restrict__ edges,   // [2][E]
                          int E,
                          unsigned short* __restrict__ ef, // [E][D] bf16 bits
                          float* __restrict__ norm)        // [E]
{
    int wave = threadIdx.x >> 6;
    int lane = threadIdx.x & 63;
    int e = blockIdx.x * 4 + wave;
    if (e >= E) return;
    int a = edges[e];
    int b = edges[E + e];
    float4 va = ((const float4*)(h + (size_t)a * D))[lane];
    float4 vb = ((const float4*)(h + (size_t)b * D))[lane];
    float4 f;
    f.x = 0.5f * (va.x + vb.x);
    f.y = 0.5f * (va.y + vb.y);
    f.z = 0.5f * (va.z + vb.z);
    f.w = 0.5f * (va.w + vb.w);
    float sq = f.x*f.x + f.y*f.y + f.z*f.z + f.w*f.w;
    ushort4 pk;
    pk.x = f2bf(f.x); pk.y = f2bf(f.y); pk.z = f2bf(f.z); pk.w = f2bf(f.w);
    ((ushort4*)(ef + (size_t)e * D))[lane] = pk;
    #pragma unroll
    for (int off = 1; off < 64; off <<= 1)
        sq += __shfl_xor(sq, off, 64);
    if (lane == 0) norm[e] = sq;
}

// ---------------- kernel 2: fused GEMM + distance + segmented min ----------------
// C = A·B^T via bf16 MFMA (16x16x32), 128x128 tile, BK=64, 4 waves/block.
// Epilogue: dist = sqrt(max(nA+nB-2*dot,0)); atomicMin into bufN / bufL.
__launch_bounds__(256, 2)
__global__ void dist_min(const unsigned short* __restrict__ A,   // ef_n [EN][D]
                         const unsigned short* __restrict__ B,   // ef_l [EL][D]
                         const float* __restrict__ normN,
                         const float* __restrict__ normL,
                         const int* __restrict__ node_batch,
                         const int* __restrict__ label_batch,
                         unsigned* __restrict__ bufN,  // [EN][NG] dist-min bits
                         unsigned* __restrict__ bufL)  // [NG][EL] dist-min bits
{
    __shared__ unsigned short As[128 * 64];
    __shared__ unsigned short Bs[128 * 64];

    const int tid  = threadIdx.x;
    const int lane = tid & 63;
    const int wave = tid >> 6;
    const int quad = lane >> 4;
    const int lc   = lane & 15;
    const int m0   = blockIdx.y * 128;
    const int n0   = blockIdx.x * 128;
    const int wr   = (wave >> 1) * 64;   // wave's row offset in tile
    const int wc   = (wave & 1) * 64;    // wave's col offset in tile

    f32x4 acc[4][4];
    #pragma unroll
    for (int i = 0; i < 4; ++i)
        #pragma unroll
        for (int j = 0; j < 4; ++j) {
            f32x4 z = {0.f, 0.f, 0.f, 0.f};
            acc[i][j] = z;
        }

    for (int kt = 0; kt < 4; ++kt) {            // K = 256 = 4 * 64
        // stage A tile: 128 rows x 64 k (16 KB) -- 16B chunks, lane-contiguous LDS
        #pragma unroll
        for (int t = 0; t < 4; ++t) {
            int c = t * 256 + tid;              // chunk id, linear in tid
            int row = c >> 3, cc = c & 7;
            const unsigned short* gp = A + (size_t)(m0 + row) * D + kt * 64 + cc * 8;
            __builtin_amdgcn_global_load_lds(
                (const __attribute__((address_space(1))) void*)gp,
                (__attribute__((address_space(3))) void*)(As + c * 8), 16, 0, 0);
        }
        #pragma unroll
        for (int t = 0; t < 4; ++t) {
            int c = t * 256 + tid;
            int row = c >> 3, cc = c & 7;
            const unsigned short* gp = B + (size_t)(n0 + row) * D + kt * 64 + cc * 8;
            __builtin_amdgcn_global_load_lds(
                (const __attribute__((address_space(1))) void*)gp,
                (__attribute__((address_space(3))) void*)(Bs + c * 8), 16, 0, 0);
        }
        __syncthreads();

        #pragma unroll
        for (int kk = 0; kk < 2; ++kk) {        // two k=32 steps
            bf16x8 af[4], bfv[4];
            #pragma unroll
            for (int mi = 0; mi < 4; ++mi)
                af[mi] = *(const bf16x8*)(As + (wr + mi*16 + lc) * 64 + kk*32 + quad*8);
            #pragma unroll
            for (int ni = 0; ni < 4; ++ni)
                bfv[ni] = *(const bf16x8*)(Bs + (wc + ni*16 + lc) * 64 + kk*32 + quad*8);
            #pragma unroll
            for (int mi = 0; mi < 4; ++mi)
                #pragma unroll
                for (int ni = 0; ni < 4; ++ni)
                    acc[mi][ni] = __builtin_amdgcn_mfma_f32_16x16x32_bf16(
                        af[mi], bfv[ni], acc[mi][ni], 0, 0, 0);
        }
        __syncthreads();
    }

    // ---- epilogue ----
    float nb[4]; int gl[4];
    #pragma unroll
    for (int ni = 0; ni < 4; ++ni) {
        int col = n0 + wc + ni*16 + lc;
        nb[ni] = normL[col];
        gl[ni] = label_batch[col];
    }
    float na[16]; int gr[16];
    #pragma unroll
    for (int mi = 0; mi < 4; ++mi)
        #pragma unroll
        for (int r = 0; r < 4; ++r) {
            int row = m0 + wr + mi*16 + quad*4 + r;
            na[mi*4 + r] = normN[row];
            gr[mi*4 + r] = node_batch[row];
        }

    // dot -> distance (in place)
    #pragma unroll
    for (int mi = 0; mi < 4; ++mi)
        #pragma unroll
        for (int ni = 0; ni < 4; ++ni)
            #pragma unroll
            for (int r = 0; r < 4; ++r) {
                float sq = na[mi*4 + r] + nb[ni] - 2.0f * acc[mi][ni][r];
                acc[mi][ni][r] = sqrtf(fmaxf(sq, 0.0f));
            }

    const float FINF = __uint_as_float(INF_BITS);

    // per-row min over columns, grouped by label graph (cols sorted by batch)
    int glo = label_batch[n0], ghi = label_batch[n0 + 127];
    for (int g = glo; g <= ghi; ++g) {
        #pragma unroll
        for (int mi = 0; mi < 4; ++mi)
            #pragma unroll
            for (int r = 0; r < 4; ++r) {
                float m = FINF;
                #pragma unroll
                for (int ni = 0; ni < 4; ++ni)
                    if (gl[ni] == g) m = fminf(m, acc[mi][ni][r]);
                m = fminf(m, __shfl_xor(m, 1, 64));
                m = fminf(m, __shfl_xor(m, 2, 64));
                m = fminf(m, __shfl_xor(m, 4, 64));
                m = fminf(m, __shfl_xor(m, 8, 64));
                if (lc == 0 && m < FINF) {
                    int row = m0 + wr + mi*16 + quad*4 + r;
                    atomicMin(&bufN[row * NG + g], __float_as_uint(m));
                }
            }
    }

    // per-col min over rows, grouped by node graph
    int rlo = node_batch[m0], rhi = node_batch[m0 + 127];
    for (int g = rlo; g <= rhi; ++g) {
        #pragma unroll
        for (int ni = 0; ni < 4; ++ni) {
            float m = FINF;
            #pragma unroll
            for (int mi = 0; mi < 4; ++mi)
                #pragma unroll
                for (int r = 0; r < 4; ++r)
                    if (gr[mi*4 + r] == g) m = fminf(m, acc[mi][ni][r]);
            m = fminf(m, __shfl_xor(m, 16, 64));
            m = fminf(m, __shfl_xor(m, 32, 64));
            if (quad == 0 && m < FINF) {
                int col = n0 + wc + ni*16 + lc;
                atomicMin(&bufL[g * EL + col], __float_as_uint(m));
            }
        }
    }
}

// ---------------- kernel 3: segment means + combine ----------------
__device__ __forceinline__ int lbound(const int* __restrict__ a, int n, int v) {
    int lo = 0, hi = n;
    while (lo < hi) { int mid = (lo + hi) >> 1; if (a[mid] < v) lo = mid + 1; else hi = mid; }
    return lo;
}

__global__ void finalize(const unsigned* __restrict__ bufN,
                         const unsigned* __restrict__ bufL,
                         const int* __restrict__ node_batch,
                         const int* __restrict__ label_batch,
                         float* __restrict__ out)
{
    int gn = blockIdx.x;     // node graph
    int t  = threadIdx.x;    // label graph

    int ns = lbound(node_batch, EN, gn);
    int ne = lbound(node_batch, EN, gn + 1);
    float sum_n = 0.0f;
    for (int i = ns; i < ne; ++i) {
        unsigned b = bufN[i * NG + t];
        if (b != INF_BITS) sum_n -= __uint_as_float(b);   // max(M) = -min(dist)
    }
    int cn = ne - ns;
    float out_n = sum_n / (float)(cn > 0 ? cn : 1);

    int ls = lbound(label_batch, EL, t);
    int le = lbound(label_batch, EL, t + 1);
    float sum_l = 0.0f;
    for (int j = ls; j < le; ++j) {
        unsigned b = bufL[gn * EL + j];
        if (b != INF_BITS) sum_l -= __uint_as_float(b);
    }
    int cl = le - ls;
    float out_l = sum_l / (float)(cl > 0 ? cl : 1);

    out[gn * NG + t] = 0.5f * (out_n + out_l);
}

extern "C" void kernel_launch(void* const* d_in, const int* in_sizes, int n_in,
                              void* d_out, int out_size, void* d_ws, size_t ws_size,
                              hipStream_t stream)
{
    const float* h          = (const float*)d_in[0];
    const int* node_edge    = (const int*)d_in[1];
    const int* node_batch   = (const int*)d_in[2];
    const int* label_edge   = (const int*)d_in[3];
    const int* label_batch  = (const int*)d_in[4];
    float* out = (float*)d_out;

    char* ws = (char*)d_ws;
    unsigned short* efn = (unsigned short*)ws; ws += (size_t)EN * D * 2;
    unsigned short* efl = (unsigned short*)ws; ws += (size_t)EL * D * 2;
    float* normN = (float*)ws;                 ws += (size_t)EN * 4;
    float* normL = (float*)ws;                 ws += (size_t)EL * 4;
    unsigned* bufN = (unsigned*)ws;            ws += (size_t)EN * NG * 4;
    unsigned* bufL = (unsigned*)ws;            ws += (size_t)NG * EL * 4;

    int ninf = EN * NG + NG * EL;
    init_inf<<<(ninf + 255) / 256, 256, 0, stream>>>(bufN, ninf);  // bufN,bufL contiguous
    edge_feat<<<EN / 4, 256, 0, stream>>>(h, node_edge, EN, efn, normN);
    edge_feat<<<EL / 4, 256, 0, stream>>>(h, label_edge, EL, efl, normL);
    dist_min<<<dim3(EL / 128, EN / 128), 256, 0, stream>>>(
        efn, efl, normN, normL, node_batch, label_batch, bufN, bufL);
    finalize<<<NG, NG, 0, stream>>>(bufN, bufL, node_batch, label_batch, out);
}

// Round 4
// 217.296 us; speedup vs baseline: 1.3352x; 1.3352x over previous
//
#include <hip/hip_runtime.h>
#include <hip/hip_bf16.h>
#include <math.h>

#define EN 8192
#define EL 8192
#define D  256
#define NG 64
#define INF_BITS 0x7f800000u

typedef __attribute__((ext_vector_type(8))) short  bf16x8;
typedef __attribute__((ext_vector_type(4))) float  f32x4;

__device__ __forceinline__ unsigned short f2bf(float f) {
    unsigned u = __float_as_uint(f);
    unsigned r = (u + 0x7fffu + ((u >> 16) & 1u)) >> 16;   // RNE
    return (unsigned short)r;
}

// ---------------- kernel 0: init min-buffers to +inf ----------------
__global__ void init_inf(unsigned* __restrict__ p, int n) {
    int i = blockIdx.x * blockDim.x + threadIdx.x;
    if (i < n) p[i] = INF_BITS;
}

// ---------------- kernel 1: edge features + norms ----------------
__global__ void edge_feat(const float* __restrict__ h,
                          const int* __restrict__ edges,   // [2][E]
                          int E,
                          unsigned short* __restrict__ ef, // [E][D] bf16 bits
                          float* __restrict__ norm)        // [E]
{
    int wave = threadIdx.x >> 6;
    int lane = threadIdx.x & 63;
    int e = blockIdx.x * 4 + wave;
    if (e >= E) return;
    int a = edges[e];
    int b = edges[E + e];
    float4 va = ((const float4*)(h + (size_t)a * D))[lane];
    float4 vb = ((const float4*)(h + (size_t)b * D))[lane];
    float4 f;
    f.x = 0.5f * (va.x + vb.x);
    f.y = 0.5f * (va.y + vb.y);
    f.z = 0.5f * (va.z + vb.z);
    f.w = 0.5f * (va.w + vb.w);
    float sq = f.x*f.x + f.y*f.y + f.z*f.z + f.w*f.w;
    ushort4 pk;
    pk.x = f2bf(f.x); pk.y = f2bf(f.y); pk.z = f2bf(f.z); pk.w = f2bf(f.w);
    ((ushort4*)(ef + (size_t)e * D))[lane] = pk;
    #pragma unroll
    for (int off = 1; off < 64; off <<= 1)
        sq += __shfl_xor(sq, off, 64);
    if (lane == 0) norm[e] = sq;
}

// ---------------- kernel 2: fused GEMM + sq-distance + segmented min ----------------
// C = A·B^T via bf16 MFMA (16x16x32), 128x128 tile, BK=64, 4 waves/block.
// LDS XOR-swizzle (phys chunk cc holds global chunk cc^(row&7)): reader's
// granule index (kchunk ^ (lc&7)) is a bijection over 8 granules for lc=0..7
// -> 2-way bank aliasing only (free per m136). global_load_lds per-lane
// GLOBAL addresses may be arbitrary; only the LDS dest is lane-ordered.
// Epilogue: sq = max(nA+nB-2*dot, 0); segmented min of SQUARED dist (sqrt
// deferred to finalize; min is order-preserving). Atomics bulk-issued under
// a single exec-mask transition; no INF guard (atomicMin(+inf) is a no-op).
__launch_bounds__(256, 3)
__global__ void dist_min(const unsigned short* __restrict__ A,   // ef_n [EN][D]
                         const unsigned short* __restrict__ B,   // ef_l [EL][D]
                         const float* __restrict__ normN,
                         const float* __restrict__ normL,
                         const int* __restrict__ node_batch,
                         const int* __restrict__ label_batch,
                         unsigned* __restrict__ bufN,  // [EN][NG] min sq-dist bits
                         unsigned* __restrict__ bufL)  // [NG][EL] min sq-dist bits
{
    __shared__ unsigned short As[128 * 64];
    __shared__ unsigned short Bs[128 * 64];

    const int tid  = threadIdx.x;
    const int lane = tid & 63;
    const int wave = tid >> 6;
    const int quad = lane >> 4;
    const int lc   = lane & 15;
    const int m0   = blockIdx.y * 128;
    const int n0   = blockIdx.x * 128;
    const int wr   = (wave >> 1) * 64;   // wave's row offset in tile
    const int wc   = (wave & 1) * 64;    // wave's col offset in tile

    f32x4 acc[4][4];
    #pragma unroll
    for (int i = 0; i < 4; ++i)
        #pragma unroll
        for (int j = 0; j < 4; ++j) {
            f32x4 z = {0.f, 0.f, 0.f, 0.f};
            acc[i][j] = z;
        }

    for (int kt = 0; kt < 4; ++kt) {            // K = 256 = 4 * 64
        // stage tiles; phys chunk (row, cc) holds global chunk (row, cc^(row&7))
        #pragma unroll
        for (int t = 0; t < 4; ++t) {
            int c = t * 256 + tid;              // chunk id, linear in tid
            int row = c >> 3, cc = c & 7;
            int scc = cc ^ (row & 7);
            const unsigned short* gp = A + (size_t)(m0 + row) * D + kt * 64 + scc * 8;
            __builtin_amdgcn_global_load_lds(
                (const __attribute__((address_space(1))) void*)gp,
                (__attribute__((address_space(3))) void*)(As + c * 8), 16, 0, 0);
        }
        #pragma unroll
        for (int t = 0; t < 4; ++t) {
            int c = t * 256 + tid;
            int row = c >> 3, cc = c & 7;
            int scc = cc ^ (row & 7);
            const unsigned short* gp = B + (size_t)(n0 + row) * D + kt * 64 + scc * 8;
            __builtin_amdgcn_global_load_lds(
                (const __attribute__((address_space(1))) void*)gp,
                (__attribute__((address_space(3))) void*)(Bs + c * 8), 16, 0, 0);
        }
        __syncthreads();

        #pragma unroll
        for (int kk = 0; kk < 2; ++kk) {        // two k=32 steps
            bf16x8 af[4], bfv[4];
            #pragma unroll
            for (int mi = 0; mi < 4; ++mi)
                af[mi] = *(const bf16x8*)(As + (wr + mi*16 + lc) * 64
                                             + ((kk*4 + quad) ^ (lc & 7)) * 8);
            #pragma unroll
            for (int ni = 0; ni < 4; ++ni)
                bfv[ni] = *(const bf16x8*)(Bs + (wc + ni*16 + lc) * 64
                                              + ((kk*4 + quad) ^ (lc & 7)) * 8);
            #pragma unroll
            for (int mi = 0; mi < 4; ++mi)
                #pragma unroll
                for (int ni = 0; ni < 4; ++ni)
                    acc[mi][ni] = __builtin_amdgcn_mfma_f32_16x16x32_bf16(
                        af[mi], bfv[ni], acc[mi][ni], 0, 0, 0);
        }
        __syncthreads();
    }

    // ---- epilogue ----
    float nb[4]; int gl[4];
    #pragma unroll
    for (int ni = 0; ni < 4; ++ni) {
        int col = n0 + wc + ni*16 + lc;
        nb[ni] = normL[col];
        gl[ni] = label_batch[col];
    }
    float na[16]; int gr[16];
    #pragma unroll
    for (int mi = 0; mi < 4; ++mi)
        #pragma unroll
        for (int r = 0; r < 4; ++r) {
            int row = m0 + wr + mi*16 + quad*4 + r;
            na[mi*4 + r] = normN[row];
            gr[mi*4 + r] = node_batch[row];
        }

    // dot -> clamped squared distance (in place); sqrt deferred to finalize
    #pragma unroll
    for (int mi = 0; mi < 4; ++mi)
        #pragma unroll
        for (int ni = 0; ni < 4; ++ni)
            #pragma unroll
            for (int r = 0; r < 4; ++r)
                acc[mi][ni][r] = fmaxf(
                    fmaf(-2.0f, acc[mi][ni][r], na[mi*4 + r] + nb[ni]), 0.0f);

    const float FINF = __uint_as_float(INF_BITS);

    // per-row min over columns, grouped by label graph (cols sorted)
    int glo = label_batch[n0], ghi = label_batch[n0 + 127];
    for (int g = glo; g <= ghi; ++g) {
        bool s0 = (gl[0] == g), s1 = (gl[1] == g), s2 = (gl[2] == g), s3 = (gl[3] == g);
        float rm[16];
        #pragma unroll
        for (int mi = 0; mi < 4; ++mi)
            #pragma unroll
            for (int r = 0; r < 4; ++r) {
                float m = s0 ? acc[mi][0][r] : FINF;
                m = fminf(m, s1 ? acc[mi][1][r] : FINF);
                m = fminf(m, s2 ? acc[mi][2][r] : FINF);
                m = fminf(m, s3 ? acc[mi][3][r] : FINF);
                m = fminf(m, __shfl_xor(m, 1, 64));
                m = fminf(m, __shfl_xor(m, 2, 64));
                m = fminf(m, __shfl_xor(m, 4, 64));
                m = fminf(m, __shfl_xor(m, 8, 64));
                rm[mi*4 + r] = m;
            }
        if (lc == 0) {   // lanes 0,16,32,48 — one per quad
            #pragma unroll
            for (int mi = 0; mi < 4; ++mi)
                #pragma unroll
                for (int r = 0; r < 4; ++r) {
                    int row = m0 + wr + mi*16 + quad*4 + r;
                    atomicMin(&bufN[row * NG + g], __float_as_uint(rm[mi*4 + r]));
                }
        }
    }

    // per-col min over rows, grouped by node graph
    int rlo = node_batch[m0], rhi = node_batch[m0 + 127];
    for (int g = rlo; g <= rhi; ++g) {
        float cm[4];
        #pragma unroll
        for (int ni = 0; ni < 4; ++ni) {
            float m = FINF;
            #pragma unroll
            for (int mi = 0; mi < 4; ++mi)
                #pragma unroll
                for (int r = 0; r < 4; ++r)
                    m = fminf(m, (gr[mi*4 + r] == g) ? acc[mi][ni][r] : FINF);
            m = fminf(m, __shfl_xor(m, 16, 64));
            m = fminf(m, __shfl_xor(m, 32, 64));
            cm[ni] = m;
        }
        if (quad == 0) {  // lanes 0..15 — one per column lc
            #pragma unroll
            for (int ni = 0; ni < 4; ++ni) {
                int col = n0 + wc + ni*16 + lc;
                atomicMin(&bufL[g * EL + col], __float_as_uint(cm[ni]));
            }
        }
    }
}

// ---------------- kernel 3: segment means + combine ----------------
__device__ __forceinline__ int lbound(const int* __restrict__ a, int n, int v) {
    int lo = 0, hi = n;
    while (lo < hi) { int mid = (lo + hi) >> 1; if (a[mid] < v) lo = mid + 1; else hi = mid; }
    return lo;
}

// one block per node-graph gn; MUST be launched with 256 threads
__global__ void finalize(const unsigned* __restrict__ bufN,
                         const unsigned* __restrict__ bufL,
                         const int* __restrict__ node_batch,
                         const int* __restrict__ label_batch,
                         float* __restrict__ out)
{
    __shared__ float sN[NG];   // sum over rows of -dist, per label graph
    __shared__ float sL[NG];   // sum over cols of -dist, per label graph
    int gn  = blockIdx.x;
    int tid = threadIdx.x;
    if (tid < NG) { sN[tid] = 0.0f; sL[tid] = 0.0f; }
    __syncthreads();

    int ns = lbound(node_batch, EN, gn);
    int ne = lbound(node_batch, EN, gn + 1);

    // part 1: bufN slice [ns:ne) x NG -> per-label sums (coalesced across t)
    {
        int t = tid & 63, strip = tid >> 6;          // 4 row strips
        float acc = 0.0f;
        for (int i = ns + strip; i < ne; i += 4) {
            unsigned b = bufN[i * NG + t];
            if (b != INF_BITS) acc -= sqrtf(__uint_as_float(b));
        }
        atomicAdd(&sN[t], acc);
    }

    // part 2: bufL row gn (8192 cols, coalesced), scatter by label graph
    for (int j = tid; j < EL; j += 256) {
        unsigned b = bufL[gn * EL + j];
        if (b != INF_BITS) {
            int g = label_batch[j];
            atomicAdd(&sL[g], -sqrtf(__uint_as_float(b)));
        }
    }
    __syncthreads();

    if (tid < NG) {
        int t = tid;
        int cn = ne - ns;
        int ls = lbound(label_batch, EL, t);
        int le = lbound(label_batch, EL, t + 1);
        int cl = le - ls;
        float out_n = sN[t] / (float)(cn > 0 ? cn : 1);
        float out_l = sL[t] / (float)(cl > 0 ? cl : 1);
        out[gn * NG + t] = 0.5f * (out_n + out_l);
    }
}

extern "C" void kernel_launch(void* const* d_in, const int* in_sizes, int n_in,
                              void* d_out, int out_size, void* d_ws, size_t ws_size,
                              hipStream_t stream)
{
    const float* h          = (const float*)d_in[0];
    const int* node_edge    = (const int*)d_in[1];
    const int* node_batch   = (const int*)d_in[2];
    const int* label_edge   = (const int*)d_in[3];
    const int* label_batch  = (const int*)d_in[4];
    float* out = (float*)d_out;

    char* ws = (char*)d_ws;
    unsigned short* efn = (unsigned short*)ws; ws += (size_t)EN * D * 2;
    unsigned short* efl = (unsigned short*)ws; ws += (size_t)EL * D * 2;
    float* normN = (float*)ws;                 ws += (size_t)EN * 4;
    float* normL = (float*)ws;                 ws += (size_t)EL * 4;
    unsigned* bufN = (unsigned*)ws;            ws += (size_t)EN * NG * 4;
    unsigned* bufL = (unsigned*)ws;            ws += (size_t)NG * EL * 4;

    int ninf = EN * NG + NG * EL;
    init_inf<<<(ninf + 255) / 256, 256, 0, stream>>>(bufN, ninf);  // bufN,bufL contiguous
    edge_feat<<<EN / 4, 256, 0, stream>>>(h, node_edge, EN, efn, normN);
    edge_feat<<<EL / 4, 256, 0, stream>>>(h, label_edge, EL, efl, normL);
    dist_min<<<dim3(EL / 128, EN / 128), 256, 0, stream>>>(
        efn, efl, normN, normL, node_batch, label_batch, bufN, bufL);
    finalize<<<NG, 256, 0, stream>>>(bufN, bufL, node_batch, label_batch, out);  // 256 thr!
}

// Round 5
// 208.446 us; speedup vs baseline: 1.3919x; 1.0425x over previous
//
#include <hip/hip_runtime.h>
#include <hip/hip_bf16.h>
#include <math.h>

#define EN 8192
#define EL 8192
#define D  256
#define NG 64
#define INF_BITS 0x7f800000u

typedef __attribute__((ext_vector_type(8))) short  bf16x8;
typedef __attribute__((ext_vector_type(4))) float  f32x4;

__device__ __forceinline__ unsigned short f2bf(float f) {
    unsigned u = __float_as_uint(f);
    unsigned r = (u + 0x7fffu + ((u >> 16) & 1u)) >> 16;   // RNE
    return (unsigned short)r;
}

// ---------------- kernel 1: fused init + edge features ----------------
// blocks [0,1024): fill bufN/bufL (contiguous 4 MB) with +inf via uint4
// blocks [1024,3072): edge features for node set
// blocks [3072,5120): edge features for label set
__global__ void prep(const float* __restrict__ h,
                     const int* __restrict__ node_edge,
                     const int* __restrict__ label_edge,
                     unsigned short* __restrict__ efn, float* __restrict__ normN,
                     unsigned short* __restrict__ efl, float* __restrict__ normL,
                     unsigned* __restrict__ inf_buf)
{
    int b = blockIdx.x;
    if (b < 1024) {
        uint4 v = make_uint4(INF_BITS, INF_BITS, INF_BITS, INF_BITS);
        ((uint4*)inf_buf)[b * 256 + threadIdx.x] = v;
        return;
    }
    b -= 1024;
    const int* edges; unsigned short* ef; float* norm;
    if (b < 2048) { edges = node_edge;  ef = efn; norm = normN; }
    else          { b -= 2048; edges = label_edge; ef = efl; norm = normL; }

    int wave = threadIdx.x >> 6;
    int lane = threadIdx.x & 63;
    int e = b * 4 + wave;
    int a  = edges[e];
    int bb = edges[EN + e];          // En == El == 8192
    float4 va = ((const float4*)(h + (size_t)a  * D))[lane];
    float4 vb = ((const float4*)(h + (size_t)bb * D))[lane];
    float4 f;
    f.x = 0.5f * (va.x + vb.x);
    f.y = 0.5f * (va.y + vb.y);
    f.z = 0.5f * (va.z + vb.z);
    f.w = 0.5f * (va.w + vb.w);
    float sq = f.x*f.x + f.y*f.y + f.z*f.z + f.w*f.w;
    ushort4 pk;
    pk.x = f2bf(f.x); pk.y = f2bf(f.y); pk.z = f2bf(f.z); pk.w = f2bf(f.w);
    ((ushort4*)(ef + (size_t)e * D))[lane] = pk;
    #pragma unroll
    for (int off = 1; off < 64; off <<= 1)
        sq += __shfl_xor(sq, off, 64);
    if (lane == 0) norm[e] = sq;
}

// ---------------- kernel 2: fused GEMM + sq-distance + segmented min ----------------
// C = A·B^T via bf16 MFMA (16x16x32), 128x128 tile, BK=64, 4 waves/block.
// LDS XOR-swizzle (phys chunk cc holds global chunk cc^(row&7)) -> 0 bank
// conflicts (verified R4). Epilogue: segmented min of SQUARED dist (sqrt in
// finalize); per-WAVE g ranges (64 sorted cols/rows span ~1-2 graphs, half
// the block's range); atomics bulk-issued; no INF guard (atomicMin(+inf) nop).
// launch_bounds(256,4): 4 blocks/CU (VGPR 76<=128, LDS 4x32KB=128<=160KB) so
// barrier drains + tail atomics of one block overlap MFMA of another.
__launch_bounds__(256, 4)
__global__ void dist_min(const unsigned short* __restrict__ A,   // ef_n [EN][D]
                         const unsigned short* __restrict__ B,   // ef_l [EL][D]
                         const float* __restrict__ normN,
                         const float* __restrict__ normL,
                         const int* __restrict__ node_batch,
                         const int* __restrict__ label_batch,
                         unsigned* __restrict__ bufN,  // [EN][NG] min sq-dist bits
                         unsigned* __restrict__ bufL)  // [NG][EL] min sq-dist bits
{
    __shared__ unsigned short As[128 * 64];
    __shared__ unsigned short Bs[128 * 64];

    const int tid  = threadIdx.x;
    const int lane = tid & 63;
    const int wave = tid >> 6;
    const int quad = lane >> 4;
    const int lc   = lane & 15;
    const int m0   = blockIdx.y * 128;
    const int n0   = blockIdx.x * 128;
    const int wr   = (wave >> 1) * 64;   // wave's row offset in tile
    const int wc   = (wave & 1) * 64;    // wave's col offset in tile

    f32x4 acc[4][4];
    #pragma unroll
    for (int i = 0; i < 4; ++i)
        #pragma unroll
        for (int j = 0; j < 4; ++j) {
            f32x4 z = {0.f, 0.f, 0.f, 0.f};
            acc[i][j] = z;
        }

    for (int kt = 0; kt < 4; ++kt) {            // K = 256 = 4 * 64
        // stage tiles; phys chunk (row, cc) holds global chunk (row, cc^(row&7))
        #pragma unroll
        for (int t = 0; t < 4; ++t) {
            int c = t * 256 + tid;              // chunk id, linear in tid
            int row = c >> 3, cc = c & 7;
            int scc = cc ^ (row & 7);
            const unsigned short* gp = A + (size_t)(m0 + row) * D + kt * 64 + scc * 8;
            __builtin_amdgcn_global_load_lds(
                (const __attribute__((address_space(1))) void*)gp,
                (__attribute__((address_space(3))) void*)(As + c * 8), 16, 0, 0);
        }
        #pragma unroll
        for (int t = 0; t < 4; ++t) {
            int c = t * 256 + tid;
            int row = c >> 3, cc = c & 7;
            int scc = cc ^ (row & 7);
            const unsigned short* gp = B + (size_t)(n0 + row) * D + kt * 64 + scc * 8;
            __builtin_amdgcn_global_load_lds(
                (const __attribute__((address_space(1))) void*)gp,
                (__attribute__((address_space(3))) void*)(Bs + c * 8), 16, 0, 0);
        }
        __syncthreads();

        #pragma unroll
        for (int kk = 0; kk < 2; ++kk) {        // two k=32 steps
            bf16x8 af[4], bfv[4];
            #pragma unroll
            for (int mi = 0; mi < 4; ++mi)
                af[mi] = *(const bf16x8*)(As + (wr + mi*16 + lc) * 64
                                             + ((kk*4 + quad) ^ (lc & 7)) * 8);
            #pragma unroll
            for (int ni = 0; ni < 4; ++ni)
                bfv[ni] = *(const bf16x8*)(Bs + (wc + ni*16 + lc) * 64
                                              + ((kk*4 + quad) ^ (lc & 7)) * 8);
            #pragma unroll
            for (int mi = 0; mi < 4; ++mi)
                #pragma unroll
                for (int ni = 0; ni < 4; ++ni)
                    acc[mi][ni] = __builtin_amdgcn_mfma_f32_16x16x32_bf16(
                        af[mi], bfv[ni], acc[mi][ni], 0, 0, 0);
        }
        __syncthreads();
    }

    // ---- epilogue ----
    float nb[4]; int gl[4];
    #pragma unroll
    for (int ni = 0; ni < 4; ++ni) {
        int col = n0 + wc + ni*16 + lc;
        nb[ni] = normL[col];
        gl[ni] = label_batch[col];
    }
    float na[16]; int gr[16];
    #pragma unroll
    for (int mi = 0; mi < 4; ++mi)
        #pragma unroll
        for (int r = 0; r < 4; ++r) {
            int row = m0 + wr + mi*16 + quad*4 + r;
            na[mi*4 + r] = normN[row];
            gr[mi*4 + r] = node_batch[row];
        }

    // dot -> clamped squared distance (in place); sqrt deferred to finalize
    #pragma unroll
    for (int mi = 0; mi < 4; ++mi)
        #pragma unroll
        for (int ni = 0; ni < 4; ++ni)
            #pragma unroll
            for (int r = 0; r < 4; ++r)
                acc[mi][ni][r] = fmaxf(
                    fmaf(-2.0f, acc[mi][ni][r], na[mi*4 + r] + nb[ni]), 0.0f);

    const float FINF = __uint_as_float(INF_BITS);

    // per-row min over columns, grouped by label graph.
    // Per-WAVE g range: this wave's 64 cols are n0+wc .. n0+wc+63 (sorted).
    int glo = label_batch[n0 + wc], ghi = label_batch[n0 + wc + 63];
    for (int g = glo; g <= ghi; ++g) {
        bool s0 = (gl[0] == g), s1 = (gl[1] == g), s2 = (gl[2] == g), s3 = (gl[3] == g);
        float rm[16];
        #pragma unroll
        for (int mi = 0; mi < 4; ++mi)
            #pragma unroll
            for (int r = 0; r < 4; ++r) {
                float m = s0 ? acc[mi][0][r] : FINF;
                m = fminf(m, s1 ? acc[mi][1][r] : FINF);
                m = fminf(m, s2 ? acc[mi][2][r] : FINF);
                m = fminf(m, s3 ? acc[mi][3][r] : FINF);
                m = fminf(m, __shfl_xor(m, 1, 64));
                m = fminf(m, __shfl_xor(m, 2, 64));
                m = fminf(m, __shfl_xor(m, 4, 64));
                m = fminf(m, __shfl_xor(m, 8, 64));
                rm[mi*4 + r] = m;
            }
        if (lc == 0) {   // lanes 0,16,32,48 — one per quad
            #pragma unroll
            for (int mi = 0; mi < 4; ++mi)
                #pragma unroll
                for (int r = 0; r < 4; ++r) {
                    int row = m0 + wr + mi*16 + quad*4 + r;
                    atomicMin(&bufN[row * NG + g], __float_as_uint(rm[mi*4 + r]));
                }
        }
    }

    // per-col min over rows, grouped by node graph.
    // Per-WAVE g range: this wave's 64 rows are m0+wr .. m0+wr+63 (sorted).
    int rlo = node_batch[m0 + wr], rhi = node_batch[m0 + wr + 63];
    for (int g = rlo; g <= rhi; ++g) {
        float cm[4];
        #pragma unroll
        for (int ni = 0; ni < 4; ++ni) {
            float m = FINF;
            #pragma unroll
            for (int mi = 0; mi < 4; ++mi)
                #pragma unroll
                for (int r = 0; r < 4; ++r)
                    m = fminf(m, (gr[mi*4 + r] == g) ? acc[mi][ni][r] : FINF);
            m = fminf(m, __shfl_xor(m, 16, 64));
            m = fminf(m, __shfl_xor(m, 32, 64));
            cm[ni] = m;
        }
        if (quad == 0) {  // lanes 0..15 — one per column lc
            #pragma unroll
            for (int ni = 0; ni < 4; ++ni) {
                int col = n0 + wc + ni*16 + lc;
                atomicMin(&bufL[g * EL + col], __float_as_uint(cm[ni]));
            }
        }
    }
}

// ---------------- kernel 3: segment means + combine ----------------
__device__ __forceinline__ int lbound(const int* __restrict__ a, int n, int v) {
    int lo = 0, hi = n;
    while (lo < hi) { int mid = (lo + hi) >> 1; if (a[mid] < v) lo = mid + 1; else hi = mid; }
    return lo;
}

// one block per node-graph gn; MUST be launched with 256 threads
__global__ void finalize(const unsigned* __restrict__ bufN,
                         const unsigned* __restrict__ bufL,
                         const int* __restrict__ node_batch,
                         const int* __restrict__ label_batch,
                         float* __restrict__ out)
{
    __shared__ float sN[NG];   // sum over rows of -dist, per label graph
    __shared__ float sL[NG];   // sum over cols of -dist, per label graph
    int gn  = blockIdx.x;
    int tid = threadIdx.x;
    if (tid < NG) { sN[tid] = 0.0f; sL[tid] = 0.0f; }
    __syncthreads();

    int ns = lbound(node_batch, EN, gn);
    int ne = lbound(node_batch, EN, gn + 1);

    // part 1: bufN slice [ns:ne) x NG -> per-label sums (coalesced across t)
    {
        int t = tid & 63, strip = tid >> 6;          // 4 row strips
        float acc = 0.0f;
        for (int i = ns + strip; i < ne; i += 4) {
            unsigned b = bufN[i * NG + t];
            if (b != INF_BITS) acc -= sqrtf(__uint_as_float(b));
        }
        atomicAdd(&sN[t], acc);
    }

    // part 2: bufL row gn (8192 cols, coalesced), scatter by label graph
    for (int j = tid; j < EL; j += 256) {
        unsigned b = bufL[gn * EL + j];
        if (b != INF_BITS) {
            int g = label_batch[j];
            atomicAdd(&sL[g], -sqrtf(__uint_as_float(b)));
        }
    }
    __syncthreads();

    if (tid < NG) {
        int t = tid;
        int cn = ne - ns;
        int ls = lbound(label_batch, EL, t);
        int le = lbound(label_batch, EL, t + 1);
        int cl = le - ls;
        float out_n = sN[t] / (float)(cn > 0 ? cn : 1);
        float out_l = sL[t] / (float)(cl > 0 ? cl : 1);
        out[gn * NG + t] = 0.5f * (out_n + out_l);
    }
}

extern "C" void kernel_launch(void* const* d_in, const int* in_sizes, int n_in,
                              void* d_out, int out_size, void* d_ws, size_t ws_size,
                              hipStream_t stream)
{
    const float* h          = (const float*)d_in[0];
    const int* node_edge    = (const int*)d_in[1];
    const int* node_batch   = (const int*)d_in[2];
    const int* label_edge   = (const int*)d_in[3];
    const int* label_batch  = (const int*)d_in[4];
    float* out = (float*)d_out;

    char* ws = (char*)d_ws;
    unsigned short* efn = (unsigned short*)ws; ws += (size_t)EN * D * 2;
    unsigned short* efl = (unsigned short*)ws; ws += (size_t)EL * D * 2;
    float* normN = (float*)ws;                 ws += (size_t)EN * 4;
    float* normL = (float*)ws;                 ws += (size_t)EL * 4;
    unsigned* bufN = (unsigned*)ws;            ws += (size_t)EN * NG * 4;
    unsigned* bufL = (unsigned*)ws;            ws += (size_t)NG * EL * 4;

    // bufN,bufL contiguous: 1024 init blocks + 2048 + 2048 edge blocks
    prep<<<5120, 256, 0, stream>>>(h, node_edge, label_edge,
                                   efn, normN, efl, normL, bufN);
    dist_min<<<dim3(EL / 128, EN / 128), 256, 0, stream>>>(
        efn, efl, normN, normL, node_batch, label_batch, bufN, bufL);
    finalize<<<NG, 256, 0, stream>>>(bufN, bufL, node_batch, label_batch, out);
}

// Round 6
// 186.132 us; speedup vs baseline: 1.5588x; 1.1199x over previous
//
#include <hip/hip_runtime.h>
#include <hip/hip_bf16.h>
#include <math.h>

#define EN 8192
#define EL 8192
#define D  256
#define NG 64
#define INF_BITS 0x7f800000u

typedef __attribute__((ext_vector_type(8))) short  bf16x8;
typedef __attribute__((ext_vector_type(4))) float  f32x4;

__device__ __forceinline__ unsigned short f2bf(float f) {
    unsigned u = __float_as_uint(f);
    unsigned r = (u + 0x7fffu + ((u >> 16) & 1u)) >> 16;   // RNE
    return (unsigned short)r;
}

// ---------------- kernel 1: fused init + edge features ----------------
// blocks [0,1024): fill bufN/bufL (contiguous 4 MB) with +inf via uint4
// blocks [1024,3072): edge features for node set
// blocks [3072,5120): edge features for label set
__global__ void prep(const float* __restrict__ h,
                     const int* __restrict__ node_edge,
                     const int* __restrict__ label_edge,
                     unsigned short* __restrict__ efn, float* __restrict__ normN,
                     unsigned short* __restrict__ efl, float* __restrict__ normL,
                     unsigned* __restrict__ inf_buf)
{
    int b = blockIdx.x;
    if (b < 1024) {
        uint4 v = make_uint4(INF_BITS, INF_BITS, INF_BITS, INF_BITS);
        ((uint4*)inf_buf)[b * 256 + threadIdx.x] = v;
        return;
    }
    b -= 1024;
    const int* edges; unsigned short* ef; float* norm;
    if (b < 2048) { edges = node_edge;  ef = efn; norm = normN; }
    else          { b -= 2048; edges = label_edge; ef = efl; norm = normL; }

    int wave = threadIdx.x >> 6;
    int lane = threadIdx.x & 63;
    int e = b * 4 + wave;
    int a  = edges[e];
    int bb = edges[EN + e];          // En == El == 8192
    float4 va = ((const float4*)(h + (size_t)a  * D))[lane];
    float4 vb = ((const float4*)(h + (size_t)bb * D))[lane];
    float4 f;
    f.x = 0.5f * (va.x + vb.x);
    f.y = 0.5f * (va.y + vb.y);
    f.z = 0.5f * (va.z + vb.z);
    f.w = 0.5f * (va.w + vb.w);
    float sq = f.x*f.x + f.y*f.y + f.z*f.z + f.w*f.w;
    ushort4 pk;
    pk.x = f2bf(f.x); pk.y = f2bf(f.y); pk.z = f2bf(f.z); pk.w = f2bf(f.w);
    ((ushort4*)(ef + (size_t)e * D))[lane] = pk;
    #pragma unroll
    for (int off = 1; off < 64; off <<= 1)
        sq += __shfl_xor(sq, off, 64);
    if (lane == 0) norm[e] = sq;
}

// ---------------- kernel 2: fused GEMM + sq-distance + segmented min ----------------
// 512 threads, 8 waves; wave-tile 32 rows x 64 cols (acc[2][4]) for 2x TLP vs
// the 4-wave version (latency-bound per R5 counters: MfmaUtil 13%, VALU 31%,
// HBM 27%, occupancy 35% -> nothing saturated). LDS XOR-swizzle -> 0 bank
// conflicts (verified R4). Epilogue has wave-uniform fast paths: if the
// wave's col window (64 cols) is single-label-graph (P~0.61) or its row
// window (32 rows) single-node-graph (P~0.79), the segmented min degenerates
// to an unsegmented min (no cndmask chains). sqrt deferred to finalize.
__launch_bounds__(512, 4)
__global__ void dist_min(const unsigned short* __restrict__ A,   // ef_n [EN][D]
                         const unsigned short* __restrict__ B,   // ef_l [EL][D]
                         const float* __restrict__ normN,
                         const float* __restrict__ normL,
                         const int* __restrict__ node_batch,
                         const int* __restrict__ label_batch,
                         unsigned* __restrict__ bufN,  // [EN][NG] min sq-dist bits
                         unsigned* __restrict__ bufL)  // [NG][EL] min sq-dist bits
{
    __shared__ unsigned short As[128 * 64];
    __shared__ unsigned short Bs[128 * 64];

    const int tid  = threadIdx.x;
    const int lane = tid & 63;
    const int wave = tid >> 6;          // 0..7
    const int quad = lane >> 4;
    const int lc   = lane & 15;
    const int m0   = blockIdx.y * 128;
    const int n0   = blockIdx.x * 128;
    const int wr   = (wave >> 1) * 32;  // 4 row groups of 32
    const int wc   = (wave & 1) * 64;   // 2 col groups of 64

    f32x4 acc[2][4];
    #pragma unroll
    for (int i = 0; i < 2; ++i)
        #pragma unroll
        for (int j = 0; j < 4; ++j) {
            f32x4 z = {0.f, 0.f, 0.f, 0.f};
            acc[i][j] = z;
        }

    for (int kt = 0; kt < 4; ++kt) {            // K = 256 = 4 * 64
        // stage tiles; phys chunk (row, cc) holds global chunk (row, cc^(row&7))
        #pragma unroll
        for (int t = 0; t < 2; ++t) {
            int c = t * 512 + tid;              // chunk id, linear in tid
            int row = c >> 3, cc = c & 7;
            int scc = cc ^ (row & 7);
            const unsigned short* gp = A + (size_t)(m0 + row) * D + kt * 64 + scc * 8;
            __builtin_amdgcn_global_load_lds(
                (const __attribute__((address_space(1))) void*)gp,
                (__attribute__((address_space(3))) void*)(As + c * 8), 16, 0, 0);
        }
        #pragma unroll
        for (int t = 0; t < 2; ++t) {
            int c = t * 512 + tid;
            int row = c >> 3, cc = c & 7;
            int scc = cc ^ (row & 7);
            const unsigned short* gp = B + (size_t)(n0 + row) * D + kt * 64 + scc * 8;
            __builtin_amdgcn_global_load_lds(
                (const __attribute__((address_space(1))) void*)gp,
                (__attribute__((address_space(3))) void*)(Bs + c * 8), 16, 0, 0);
        }
        __syncthreads();

        #pragma unroll
        for (int kk = 0; kk < 2; ++kk) {        // two k=32 steps
            bf16x8 af[2], bfv[4];
            #pragma unroll
            for (int mi = 0; mi < 2; ++mi)
                af[mi] = *(const bf16x8*)(As + (wr + mi*16 + lc) * 64
                                             + ((kk*4 + quad) ^ (lc & 7)) * 8);
            #pragma unroll
            for (int ni = 0; ni < 4; ++ni)
                bfv[ni] = *(const bf16x8*)(Bs + (wc + ni*16 + lc) * 64
                                              + ((kk*4 + quad) ^ (lc & 7)) * 8);
            #pragma unroll
            for (int mi = 0; mi < 2; ++mi)
                #pragma unroll
                for (int ni = 0; ni < 4; ++ni)
                    acc[mi][ni] = __builtin_amdgcn_mfma_f32_16x16x32_bf16(
                        af[mi], bfv[ni], acc[mi][ni], 0, 0, 0);
        }
        __syncthreads();
    }

    // ---- epilogue ----
    float nb[4]; int gl[4];
    #pragma unroll
    for (int ni = 0; ni < 4; ++ni) {
        int col = n0 + wc + ni*16 + lc;
        nb[ni] = normL[col];
        gl[ni] = label_batch[col];
    }
    float na[8]; int gr[8];
    #pragma unroll
    for (int mi = 0; mi < 2; ++mi)
        #pragma unroll
        for (int r = 0; r < 4; ++r) {
            int row = m0 + wr + mi*16 + quad*4 + r;
            na[mi*4 + r] = normN[row];
            gr[mi*4 + r] = node_batch[row];
        }

    // dot -> clamped squared distance (in place); sqrt deferred to finalize
    #pragma unroll
    for (int mi = 0; mi < 2; ++mi)
        #pragma unroll
        for (int ni = 0; ni < 4; ++ni)
            #pragma unroll
            for (int r = 0; r < 4; ++r)
                acc[mi][ni][r] = fmaxf(
                    fmaf(-2.0f, acc[mi][ni][r], na[mi*4 + r] + nb[ni]), 0.0f);

    const float FINF = __uint_as_float(INF_BITS);

    // ---- per-row min over columns, grouped by label graph ----
    // wave col window = [n0+wc, n0+wc+63] (sorted by label_batch)
    int glo = label_batch[n0 + wc], ghi = label_batch[n0 + wc + 63];
    if (glo == ghi) {
        // fast path: single label graph -> unsegmented min over 64 cols
        float rm[8];
        #pragma unroll
        for (int mi = 0; mi < 2; ++mi)
            #pragma unroll
            for (int r = 0; r < 4; ++r) {
                float m = fminf(fminf(acc[mi][0][r], acc[mi][1][r]),
                                fminf(acc[mi][2][r], acc[mi][3][r]));
                m = fminf(m, __shfl_xor(m, 1, 64));
                m = fminf(m, __shfl_xor(m, 2, 64));
                m = fminf(m, __shfl_xor(m, 4, 64));
                m = fminf(m, __shfl_xor(m, 8, 64));
                rm[mi*4 + r] = m;
            }
        if (lc == 0) {
            #pragma unroll
            for (int mi = 0; mi < 2; ++mi)
                #pragma unroll
                for (int r = 0; r < 4; ++r) {
                    int row = m0 + wr + mi*16 + quad*4 + r;
                    atomicMin(&bufN[row * NG + glo], __float_as_uint(rm[mi*4 + r]));
                }
        }
    } else {
        for (int g = glo; g <= ghi; ++g) {
            bool s0 = (gl[0] == g), s1 = (gl[1] == g), s2 = (gl[2] == g), s3 = (gl[3] == g);
            float rm[8];
            #pragma unroll
            for (int mi = 0; mi < 2; ++mi)
                #pragma unroll
                for (int r = 0; r < 4; ++r) {
                    float m = s0 ? acc[mi][0][r] : FINF;
                    m = fminf(m, s1 ? acc[mi][1][r] : FINF);
                    m = fminf(m, s2 ? acc[mi][2][r] : FINF);
                    m = fminf(m, s3 ? acc[mi][3][r] : FINF);
                    m = fminf(m, __shfl_xor(m, 1, 64));
                    m = fminf(m, __shfl_xor(m, 2, 64));
                    m = fminf(m, __shfl_xor(m, 4, 64));
                    m = fminf(m, __shfl_xor(m, 8, 64));
                    rm[mi*4 + r] = m;
                }
            if (lc == 0) {
                #pragma unroll
                for (int mi = 0; mi < 2; ++mi)
                    #pragma unroll
                    for (int r = 0; r < 4; ++r) {
                        int row = m0 + wr + mi*16 + quad*4 + r;
                        atomicMin(&bufN[row * NG + g], __float_as_uint(rm[mi*4 + r]));
                    }
            }
        }
    }

    // ---- per-col min over rows, grouped by node graph ----
    // wave row window = [m0+wr, m0+wr+31] (sorted by node_batch)
    int rlo = node_batch[m0 + wr], rhi = node_batch[m0 + wr + 31];
    if (rlo == rhi) {
        // fast path: single node graph -> unsegmented min over 32 rows
        float cm[4];
        #pragma unroll
        for (int ni = 0; ni < 4; ++ni) {
            float m = acc[0][ni][0];
            m = fminf(m, acc[0][ni][1]); m = fminf(m, acc[0][ni][2]);
            m = fminf(m, acc[0][ni][3]); m = fminf(m, acc[1][ni][0]);
            m = fminf(m, acc[1][ni][1]); m = fminf(m, acc[1][ni][2]);
            m = fminf(m, acc[1][ni][3]);
            m = fminf(m, __shfl_xor(m, 16, 64));
            m = fminf(m, __shfl_xor(m, 32, 64));
            cm[ni] = m;
        }
        if (quad == 0) {
            #pragma unroll
            for (int ni = 0; ni < 4; ++ni) {
                int col = n0 + wc + ni*16 + lc;
                atomicMin(&bufL[rlo * EL + col], __float_as_uint(cm[ni]));
            }
        }
    } else {
        for (int g = rlo; g <= rhi; ++g) {
            float cm[4];
            #pragma unroll
            for (int ni = 0; ni < 4; ++ni) {
                float m = FINF;
                #pragma unroll
                for (int mi = 0; mi < 2; ++mi)
                    #pragma unroll
                    for (int r = 0; r < 4; ++r)
                        m = fminf(m, (gr[mi*4 + r] == g) ? acc[mi][ni][r] : FINF);
                m = fminf(m, __shfl_xor(m, 16, 64));
                m = fminf(m, __shfl_xor(m, 32, 64));
                cm[ni] = m;
            }
            if (quad == 0) {
                #pragma unroll
                for (int ni = 0; ni < 4; ++ni) {
                    int col = n0 + wc + ni*16 + lc;
                    atomicMin(&bufL[g * EL + col], __float_as_uint(cm[ni]));
                }
            }
        }
    }
}

// ---------------- kernel 3: segment means + combine ----------------
__device__ __forceinline__ int lbound(const int* __restrict__ a, int n, int v) {
    int lo = 0, hi = n;
    while (lo < hi) { int mid = (lo + hi) >> 1; if (a[mid] < v) lo = mid + 1; else hi = mid; }
    return lo;
}

// one block per node-graph gn; MUST be launched with 1024 threads
__global__ void finalize(const unsigned* __restrict__ bufN,
                         const unsigned* __restrict__ bufL,
                         const int* __restrict__ node_batch,
                         const int* __restrict__ label_batch,
                         float* __restrict__ out)
{
    __shared__ float sN[NG];   // sum over rows of -dist, per label graph
    __shared__ float sL[NG];   // sum over cols of -dist, per label graph
    int gn  = blockIdx.x;
    int tid = threadIdx.x;
    if (tid < NG) { sN[tid] = 0.0f; sL[tid] = 0.0f; }
    __syncthreads();

    int ns = lbound(node_batch, EN, gn);
    int ne = lbound(node_batch, EN, gn + 1);

    // part 1: bufN slice [ns:ne) x NG -> per-label sums (coalesced across t)
    {
        int t = tid & 63, strip = tid >> 6;          // 16 row strips
        float acc = 0.0f;
        for (int i = ns + strip; i < ne; i += 16) {
            unsigned b = bufN[i * NG + t];
            if (b != INF_BITS) acc -= sqrtf(__uint_as_float(b));
        }
        atomicAdd(&sN[t], acc);
    }

    // part 2: bufL row gn (8192 cols, coalesced), scatter by label graph
    for (int j = tid; j < EL; j += 1024) {
        unsigned b = bufL[gn * EL + j];
        if (b != INF_BITS) {
            int g = label_batch[j];
            atomicAdd(&sL[g], -sqrtf(__uint_as_float(b)));
        }
    }
    __syncthreads();

    if (tid < NG) {
        int t = tid;
        int cn = ne - ns;
        int ls = lbound(label_batch, EL, t);
        int le = lbound(label_batch, EL, t + 1);
        int cl = le - ls;
        float out_n = sN[t] / (float)(cn > 0 ? cn : 1);
        float out_l = sL[t] / (float)(cl > 0 ? cl : 1);
        out[gn * NG + t] = 0.5f * (out_n + out_l);
    }
}

extern "C" void kernel_launch(void* const* d_in, const int* in_sizes, int n_in,
                              void* d_out, int out_size, void* d_ws, size_t ws_size,
                              hipStream_t stream)
{
    const float* h          = (const float*)d_in[0];
    const int* node_edge    = (const int*)d_in[1];
    const int* node_batch   = (const int*)d_in[2];
    const int* label_edge   = (const int*)d_in[3];
    const int* label_batch  = (const int*)d_in[4];
    float* out = (float*)d_out;

    char* ws = (char*)d_ws;
    unsigned short* efn = (unsigned short*)ws; ws += (size_t)EN * D * 2;
    unsigned short* efl = (unsigned short*)ws; ws += (size_t)EL * D * 2;
    float* normN = (float*)ws;                 ws += (size_t)EN * 4;
    float* normL = (float*)ws;                 ws += (size_t)EL * 4;
    unsigned* bufN = (unsigned*)ws;            ws += (size_t)EN * NG * 4;
    unsigned* bufL = (unsigned*)ws;            ws += (size_t)NG * EL * 4;

    // bufN,bufL contiguous: 1024 init blocks + 2048 + 2048 edge blocks
    prep<<<5120, 256, 0, stream>>>(h, node_edge, label_edge,
                                   efn, normN, efl, normL, bufN);
    dist_min<<<dim3(EL / 128, EN / 128), 512, 0, stream>>>(
        efn, efl, normN, normL, node_batch, label_batch, bufN, bufL);
    finalize<<<NG, 1024, 0, stream>>>(bufN, bufL, node_batch, label_batch, out);
}